// Round 2
// baseline (5161.306 us; speedup 1.0000x reference)
//
#include <hip/hip_runtime.h>

// Sizes (fixed by the reference)
#define D_MODEL 1024
#define N_HEAD  16
#define DK      64
#define BATCH   8
#define LSEQ    1024
#define MROWS   (BATCH * LSEQ)          // 8192
#define SCALE   0.03125f                // 1/sqrt(1024)
#define NEGBIG  (-3.0e38f)

// ---------------------------------------------------------------------------
// Kernel 1: per-head QKV projections.
// S[h,b,l,k] = sum_d X[b,l,d] * W[h,d,k]
// One z-slice per input (q/k/v). blockIdx.x = head (64 output cols),
// blockIdx.y = 64-row tile of M. 64x64x32 tile, 256 thr, 4x4 micro-tile.
// ---------------------------------------------------------------------------
__global__ __launch_bounds__(256) void qkv_proj_kernel(
    const float* __restrict__ Xq, const float* __restrict__ Xk, const float* __restrict__ Xv,
    const float* __restrict__ Wq, const float* __restrict__ Wk, const float* __restrict__ Wv,
    float* __restrict__ Sq, float* __restrict__ Sk, float* __restrict__ Sv)
{
    const int which = blockIdx.z;
    const float* __restrict__ X = (which == 0) ? Xq : (which == 1) ? Xk : Xv;
    const float* __restrict__ W = (which == 0) ? Wq : (which == 1) ? Wk : Wv;
    float* __restrict__ S       = (which == 0) ? Sq : (which == 1) ? Sk : Sv;

    const int h  = blockIdx.x;
    const int m0 = blockIdx.y * 64;

    __shared__ float As[32][68];   // [k][m], padded
    __shared__ float Bs[32][68];   // [k][n], padded

    const int tid = threadIdx.x;
    const int tx  = tid & 15;
    const int ty  = tid >> 4;

    // A-load mapping: 64 rows x 32 k, 8 floats/thread (2 float4)
    const int mA  = tid >> 2;
    const int kqA = (tid & 3) * 8;
    // B-load mapping: W[h] is (1024 d x 64 n) row-major, rows contiguous in n
    const int dB  = tid >> 4;          // 0..15 (and +16)
    const int nqB = (tid & 15) * 4;

    const float* Wh = W + (size_t)h * (D_MODEL * DK);

    float acc[4][4] = {{0.f, 0.f, 0.f, 0.f}, {0.f, 0.f, 0.f, 0.f},
                       {0.f, 0.f, 0.f, 0.f}, {0.f, 0.f, 0.f, 0.f}};

    for (int k0 = 0; k0 < D_MODEL; k0 += 32) {
        float4 a0 = *(const float4*)(X + (size_t)(m0 + mA) * D_MODEL + k0 + kqA);
        float4 a1 = *(const float4*)(X + (size_t)(m0 + mA) * D_MODEL + k0 + kqA + 4);
        float4 b0 = *(const float4*)(Wh + (size_t)(k0 + dB) * DK + nqB);
        float4 b1 = *(const float4*)(Wh + (size_t)(k0 + dB + 16) * DK + nqB);
        As[kqA + 0][mA] = a0.x; As[kqA + 1][mA] = a0.y;
        As[kqA + 2][mA] = a0.z; As[kqA + 3][mA] = a0.w;
        As[kqA + 4][mA] = a1.x; As[kqA + 5][mA] = a1.y;
        As[kqA + 6][mA] = a1.z; As[kqA + 7][mA] = a1.w;
        *(float4*)&Bs[dB][nqB]      = b0;
        *(float4*)&Bs[dB + 16][nqB] = b1;
        __syncthreads();
        #pragma unroll
        for (int kk = 0; kk < 32; ++kk) {
            float4 av = *(const float4*)&As[kk][ty * 4];
            float4 bv = *(const float4*)&Bs[kk][tx * 4];
            float a[4] = {av.x, av.y, av.z, av.w};
            float b[4] = {bv.x, bv.y, bv.z, bv.w};
            #pragma unroll
            for (int i = 0; i < 4; ++i)
                #pragma unroll
                for (int j = 0; j < 4; ++j)
                    acc[i][j] += a[i] * b[j];
        }
        __syncthreads();
    }

    const int b  = m0 >> 10;     // L = 1024, tiles never cross batch boundary
    const int l0 = m0 & 1023;
    float* Sb = S + (size_t)(h * BATCH + b) * LSEQ * DK;
    #pragma unroll
    for (int i = 0; i < 4; ++i) {
        int l = l0 + ty * 4 + i;
        float4 o = {acc[i][0], acc[i][1], acc[i][2], acc[i][3]};
        *(float4*)(Sb + (size_t)l * DK + tx * 4) = o;
    }
}

// ---------------------------------------------------------------------------
// Kernel 2: attention for one (h,b) pair and one 64-row q tile.
// Two-pass online softmax (no LxL score storage). Writes normalized attn
// probabilities into d_out's attns region (coalesced float4 from LDS), and
// the per-head output into OH laid out [b][l][h*64+v] (pre-concatenated for
// the projection GEMM).
// ---------------------------------------------------------------------------
__global__ __launch_bounds__(256) void attn_kernel(
    const float* __restrict__ QS, const float* __restrict__ KS, const float* __restrict__ VS,
    const unsigned char* __restrict__ mask,
    float* __restrict__ attns, float* __restrict__ OH)
{
    const int qt = blockIdx.x;       // 0..15
    const int hb = blockIdx.y;       // h*8 + b
    const int h  = hb >> 3;
    const int b  = hb & 7;
    const int q0 = qt * 64;

    __shared__ float Qs[64][68];     // [q][d]
    __shared__ float Ks[64][68];     // [k][d]
    __shared__ float Vt[64][68];     // transposed: [v][k]
    __shared__ float Ps[64][68];     // probabilities [q][k] (also m/s reduce buf)
    __shared__ uint4 Ms[256];        // mask tile bytes
    __shared__ int   mflag[4];

    const int tid = threadIdx.x;
    const int tx  = tid & 15;
    const int ty  = tid >> 4;

    const float* Qg = QS + ((size_t)hb * LSEQ + q0) * DK;
    const float* Kg = KS + (size_t)hb * LSEQ * DK;
    const float* Vg = VS + (size_t)hb * LSEQ * DK;
    const unsigned char* Mg = mask + (size_t)b * LSEQ * LSEQ + (size_t)q0 * LSEQ;
    float* Ag = attns + ((size_t)hb * LSEQ + q0) * LSEQ;

    const int qrow[4] = {ty, ty + 16, ty + 32, ty + 48};
    const int kcol[4] = {tx, tx + 16, tx + 32, tx + 48};

    // mask tile staging indices: row = tid>>2, 16 bytes at col (tid&3)*16
    const int mq = tid >> 2;
    const int mc = (tid & 3) * 16;

    // ---- load Q tile (4096 contiguous floats) ----
    {
        const float4* s4 = (const float4*)Qg;
        #pragma unroll
        for (int i = 0; i < 4; ++i) {
            int f = i * 256 + tid;
            float4 val = s4[f];
            *(float4*)&Qs[f >> 4][(f & 15) * 4] = val;
        }
    }

    float mloc[4], sloc[4];
    #pragma unroll
    for (int i = 0; i < 4; ++i) { mloc[i] = NEGBIG; sloc[i] = 0.f; }

    // =================== pass 1: row max + sum of exp ===================
    for (int kt = 0; kt < 16; ++kt) {
        {
            const float4* s4 = (const float4*)(Kg + (size_t)kt * 4096);
            #pragma unroll
            for (int i = 0; i < 4; ++i) {
                int f = i * 256 + tid;
                float4 val = s4[f];
                *(float4*)&Ks[f >> 4][(f & 15) * 4] = val;
            }
            uint4 mv = *(const uint4*)(Mg + (size_t)mq * LSEQ + kt * 64 + mc);
            Ms[tid] = mv;
            unsigned long long bal = __ballot((mv.x | mv.y | mv.z | mv.w) != 0u);
            if ((tid & 63) == 0) mflag[tid >> 6] = (bal != 0ull);
        }
        __syncthreads();
        const int anym = mflag[0] | mflag[1] | mflag[2] | mflag[3];

        float sc[4][4] = {{0.f, 0.f, 0.f, 0.f}, {0.f, 0.f, 0.f, 0.f},
                          {0.f, 0.f, 0.f, 0.f}, {0.f, 0.f, 0.f, 0.f}};
        for (int d = 0; d < 64; d += 4) {
            float4 qv[4], kv[4];
            #pragma unroll
            for (int i = 0; i < 4; ++i) qv[i] = *(const float4*)&Qs[qrow[i]][d];
            #pragma unroll
            for (int j = 0; j < 4; ++j) kv[j] = *(const float4*)&Ks[kcol[j]][d];
            #pragma unroll
            for (int i = 0; i < 4; ++i)
                #pragma unroll
                for (int j = 0; j < 4; ++j)
                    sc[i][j] += qv[i].x * kv[j].x + qv[i].y * kv[j].y +
                                qv[i].z * kv[j].z + qv[i].w * kv[j].w;
        }
        #pragma unroll
        for (int i = 0; i < 4; ++i) {
            float s0 = sc[i][0] * SCALE, s1 = sc[i][1] * SCALE;
            float s2 = sc[i][2] * SCALE, s3 = sc[i][3] * SCALE;
            if (anym) {
                const unsigned char* mb = (const unsigned char*)Ms + qrow[i] * 64;
                if (mb[kcol[0]]) s0 = NEGBIG;
                if (mb[kcol[1]]) s1 = NEGBIG;
                if (mb[kcol[2]]) s2 = NEGBIG;
                if (mb[kcol[3]]) s3 = NEGBIG;
            }
            float tm = fmaxf(fmaxf(s0, s1), fmaxf(s2, s3));
            float nm = fmaxf(mloc[i], tm);
            sloc[i] = sloc[i] * __expf(mloc[i] - nm) +
                      __expf(s0 - nm) + __expf(s1 - nm) + __expf(s2 - nm) + __expf(s3 - nm);
            mloc[i] = nm;
        }
        __syncthreads();
    }

    // ---- reduce (m, s) across the 16 tx threads of each q row via Ps ----
    #pragma unroll
    for (int i = 0; i < 4; ++i) {
        Ps[qrow[i]][tx]      = mloc[i];
        Ps[qrow[i]][tx + 16] = sloc[i];
    }
    __syncthreads();
    float mfin[4], sinv[4];
    #pragma unroll
    for (int i = 0; i < 4; ++i) {
        float m = NEGBIG;
        #pragma unroll
        for (int t = 0; t < 16; ++t) m = fmaxf(m, Ps[qrow[i]][t]);
        float s = 0.f;
        #pragma unroll
        for (int t = 0; t < 16; ++t) s += Ps[qrow[i]][t + 16] * __expf(Ps[qrow[i]][t] - m);
        mfin[i] = m;
        sinv[i] = 1.f / s;
    }
    __syncthreads();

    // =================== pass 2: normalized P, attn write, PV ===================
    float acc[4][4] = {{0.f, 0.f, 0.f, 0.f}, {0.f, 0.f, 0.f, 0.f},
                       {0.f, 0.f, 0.f, 0.f}, {0.f, 0.f, 0.f, 0.f}};

    for (int kt = 0; kt < 16; ++kt) {
        {
            const float4* s4 = (const float4*)(Kg + (size_t)kt * 4096);
            const float4* v4 = (const float4*)(Vg + (size_t)kt * 4096);
            #pragma unroll
            for (int i = 0; i < 4; ++i) {
                int f = i * 256 + tid;
                float4 val = s4[f];
                *(float4*)&Ks[f >> 4][(f & 15) * 4] = val;
                float4 vv = v4[f];
                int kkr = f >> 4, v0 = (f & 15) * 4;
                Vt[v0 + 0][kkr] = vv.x; Vt[v0 + 1][kkr] = vv.y;
                Vt[v0 + 2][kkr] = vv.z; Vt[v0 + 3][kkr] = vv.w;
            }
            uint4 mv = *(const uint4*)(Mg + (size_t)mq * LSEQ + kt * 64 + mc);
            Ms[tid] = mv;
            unsigned long long bal = __ballot((mv.x | mv.y | mv.z | mv.w) != 0u);
            if ((tid & 63) == 0) mflag[tid >> 6] = (bal != 0ull);
        }
        __syncthreads();
        const int anym = mflag[0] | mflag[1] | mflag[2] | mflag[3];

        float sc[4][4] = {{0.f, 0.f, 0.f, 0.f}, {0.f, 0.f, 0.f, 0.f},
                          {0.f, 0.f, 0.f, 0.f}, {0.f, 0.f, 0.f, 0.f}};
        for (int d = 0; d < 64; d += 4) {
            float4 qv[4], kv[4];
            #pragma unroll
            for (int i = 0; i < 4; ++i) qv[i] = *(const float4*)&Qs[qrow[i]][d];
            #pragma unroll
            for (int j = 0; j < 4; ++j) kv[j] = *(const float4*)&Ks[kcol[j]][d];
            #pragma unroll
            for (int i = 0; i < 4; ++i)
                #pragma unroll
                for (int j = 0; j < 4; ++j)
                    sc[i][j] += qv[i].x * kv[j].x + qv[i].y * kv[j].y +
                                qv[i].z * kv[j].z + qv[i].w * kv[j].w;
        }
        #pragma unroll
        for (int i = 0; i < 4; ++i) {
            #pragma unroll
            for (int j = 0; j < 4; ++j) {
                float s = sc[i][j] * SCALE;
                float p = __expf(s - mfin[i]) * sinv[i];
                if (anym && ((const unsigned char*)Ms)[qrow[i] * 64 + kcol[j]]) p = 0.f;
                Ps[qrow[i]][kcol[j]] = p;
            }
        }
        __syncthreads();

        // ---- coalesced attn-probability write: float4 rows from LDS ----
        #pragma unroll
        for (int i = 0; i < 4; ++i) {
            int idx = i * 256 + tid;          // 0..1023
            int r   = idx >> 4;               // 0..63
            int c4  = (idx & 15) * 4;         // 0..60
            float4 pv4 = *(const float4*)&Ps[r][c4];
            *(float4*)(Ag + (size_t)r * LSEQ + kt * 64 + c4) = pv4;
        }

        // PV: acc[q][v] += sum_k P[q][k] * V[k][v]   (Vt is [v][k])
        for (int kk = 0; kk < 64; kk += 4) {
            float4 pv[4], vv[4];
            #pragma unroll
            for (int i = 0; i < 4; ++i) pv[i] = *(const float4*)&Ps[qrow[i]][kk];
            #pragma unroll
            for (int j = 0; j < 4; ++j) vv[j] = *(const float4*)&Vt[kcol[j]][kk];
            #pragma unroll
            for (int i = 0; i < 4; ++i)
                #pragma unroll
                for (int j = 0; j < 4; ++j)
                    acc[i][j] += pv[i].x * vv[j].x + pv[i].y * vv[j].y +
                                 pv[i].z * vv[j].z + pv[i].w * vv[j].w;
        }
        __syncthreads();
    }

    // ---- write OH[b][l][h*64+v] ----
    #pragma unroll
    for (int i = 0; i < 4; ++i) {
        size_t base = ((size_t)b * LSEQ + q0 + qrow[i]) * D_MODEL + h * DK;
        #pragma unroll
        for (int j = 0; j < 4; ++j)
            OH[base + kcol[j]] = acc[i][j];
    }
}

// ---------------------------------------------------------------------------
// Kernel 3: output projection + bias + residual.
// Xo[m][n] = sum_i OH[m][i] * Pw[n][i] + pb[n] + R[m][n]
// ---------------------------------------------------------------------------
__global__ __launch_bounds__(256) void out_proj_kernel(
    const float* __restrict__ O, const float* __restrict__ Pw, const float* __restrict__ pb,
    const float* __restrict__ R, float* __restrict__ Xo)
{
    const int n0 = blockIdx.x * 64;
    const int m0 = blockIdx.y * 64;

    __shared__ float As[32][68];   // [k][m]
    __shared__ float Bs[32][68];   // [k][n]

    const int tid = threadIdx.x;
    const int tx  = tid & 15;
    const int ty  = tid >> 4;

    const int rA = tid >> 2;           // 0..63: row of A (m) / row of B (n)
    const int kq = (tid & 3) * 8;

    float acc[4][4] = {{0.f, 0.f, 0.f, 0.f}, {0.f, 0.f, 0.f, 0.f},
                       {0.f, 0.f, 0.f, 0.f}, {0.f, 0.f, 0.f, 0.f}};

    for (int k0 = 0; k0 < D_MODEL; k0 += 32) {
        float4 a0 = *(const float4*)(O  + (size_t)(m0 + rA) * D_MODEL + k0 + kq);
        float4 a1 = *(const float4*)(O  + (size_t)(m0 + rA) * D_MODEL + k0 + kq + 4);
        float4 b0 = *(const float4*)(Pw + (size_t)(n0 + rA) * D_MODEL + k0 + kq);
        float4 b1 = *(const float4*)(Pw + (size_t)(n0 + rA) * D_MODEL + k0 + kq + 4);
        As[kq + 0][rA] = a0.x; As[kq + 1][rA] = a0.y;
        As[kq + 2][rA] = a0.z; As[kq + 3][rA] = a0.w;
        As[kq + 4][rA] = a1.x; As[kq + 5][rA] = a1.y;
        As[kq + 6][rA] = a1.z; As[kq + 7][rA] = a1.w;
        Bs[kq + 0][rA] = b0.x; Bs[kq + 1][rA] = b0.y;
        Bs[kq + 2][rA] = b0.z; Bs[kq + 3][rA] = b0.w;
        Bs[kq + 4][rA] = b1.x; Bs[kq + 5][rA] = b1.y;
        Bs[kq + 6][rA] = b1.z; Bs[kq + 7][rA] = b1.w;
        __syncthreads();
        #pragma unroll
        for (int kk = 0; kk < 32; ++kk) {
            float4 av = *(const float4*)&As[kk][ty * 4];
            float4 bv = *(const float4*)&Bs[kk][tx * 4];
            float a[4] = {av.x, av.y, av.z, av.w};
            float b[4] = {bv.x, bv.y, bv.z, bv.w};
            #pragma unroll
            for (int i = 0; i < 4; ++i)
                #pragma unroll
                for (int j = 0; j < 4; ++j)
                    acc[i][j] += a[i] * b[j];
        }
        __syncthreads();
    }

    #pragma unroll
    for (int i = 0; i < 4; ++i) {
        int m = m0 + ty * 4 + i;
        int n = n0 + tx * 4;
        float4 pbv = *(const float4*)(pb + n);
        float4 rv  = *(const float4*)(R + (size_t)m * D_MODEL + n);
        float4 o;
        o.x = acc[i][0] + pbv.x + rv.x;
        o.y = acc[i][1] + pbv.y + rv.y;
        o.z = acc[i][2] + pbv.z + rv.z;
        o.w = acc[i][3] + pbv.w + rv.w;
        *(float4*)(Xo + (size_t)m * D_MODEL + n) = o;
    }
}

// ---------------------------------------------------------------------------
// Kernel 4: LayerNorm, in place on d_out's outputs region. One block per row.
// Two-pass (mean, then var of deviations) to match jnp.var numerics.
// ---------------------------------------------------------------------------
__global__ __launch_bounds__(256) void ln_kernel(
    float* __restrict__ x, const float* __restrict__ g, const float* __restrict__ bt)
{
    const int row = blockIdx.x;
    float* xr = x + (size_t)row * D_MODEL;
    const int tid = threadIdx.x;

    __shared__ float red[4];

    float4 v = ((const float4*)xr)[tid];
    float s = v.x + v.y + v.z + v.w;
    #pragma unroll
    for (int o = 1; o < 64; o <<= 1) s += __shfl_xor(s, o);
    if ((tid & 63) == 0) red[tid >> 6] = s;
    __syncthreads();
    s = red[0] + red[1] + red[2] + red[3];
    const float mean = s * (1.f / 1024.f);

    float dx = v.x - mean, dy = v.y - mean, dz = v.z - mean, dw = v.w - mean;
    float sq = dx * dx + dy * dy + dz * dz + dw * dw;
    #pragma unroll
    for (int o = 1; o < 64; o <<= 1) sq += __shfl_xor(sq, o);
    __syncthreads();
    if ((tid & 63) == 0) red[tid >> 6] = sq;
    __syncthreads();
    sq = red[0] + red[1] + red[2] + red[3];
    const float rstd = rsqrtf(sq * (1.f / 1024.f) + 1e-5f);

    float4 gv = ((const float4*)g)[tid];
    float4 bv = ((const float4*)bt)[tid];
    float4 o4;
    o4.x = dx * rstd * gv.x + bv.x;
    o4.y = dy * rstd * gv.y + bv.y;
    o4.z = dz * rstd * gv.z + bv.z;
    o4.w = dw * rstd * gv.w + bv.w;
    ((float4*)xr)[tid] = o4;
}

// ---------------------------------------------------------------------------
extern "C" void kernel_launch(void* const* d_in, const int* in_sizes, int n_in,
                              void* d_out, int out_size, void* d_ws, size_t ws_size,
                              hipStream_t stream)
{
    const float* q      = (const float*)d_in[0];
    const float* k      = (const float*)d_in[1];
    const float* v      = (const float*)d_in[2];
    const unsigned char* mask = (const unsigned char*)d_in[3];  // bool array, 1B/elem
    const float* w_qs   = (const float*)d_in[4];
    const float* w_ks   = (const float*)d_in[5];
    const float* w_vs   = (const float*)d_in[6];
    const float* proj_w = (const float*)d_in[7];
    const float* proj_b = (const float*)d_in[8];
    const float* ln_g   = (const float*)d_in[9];
    const float* ln_b   = (const float*)d_in[10];

    float* outputs = (float*)d_out;                                  // B*L*D
    float* attns   = (float*)d_out + (size_t)BATCH * LSEQ * D_MODEL; // H*B*L*L

    // workspace: qs | ks | vs | oh  (4 x 32 MB = 128 MB)
    float* qs = (float*)d_ws;
    float* ks = qs + (size_t)N_HEAD * BATCH * LSEQ * DK;
    float* vs = ks + (size_t)N_HEAD * BATCH * LSEQ * DK;
    float* oh = vs + (size_t)N_HEAD * BATCH * LSEQ * DK;

    dim3 blk(256);
    qkv_proj_kernel<<<dim3(N_HEAD, MROWS / 64, 3), blk, 0, stream>>>(
        q, k, v, w_qs, w_ks, w_vs, qs, ks, vs);
    attn_kernel<<<dim3(LSEQ / 64, N_HEAD * BATCH), blk, 0, stream>>>(
        qs, ks, vs, mask, attns, oh);
    out_proj_kernel<<<dim3(D_MODEL / 64, MROWS / 64), blk, 0, stream>>>(
        oh, proj_w, proj_b, q, outputs);
    ln_kernel<<<dim3(MROWS), blk, 0, stream>>>(outputs, ln_g, ln_b);
}

// Round 4
// 1807.441 us; speedup vs baseline: 2.8556x; 2.8556x over previous
//
#include <hip/hip_runtime.h>

// Sizes (fixed by the reference)
#define D_MODEL 1024
#define N_HEAD  16
#define DK      64
#define BATCH   8
#define LSEQ    1024
#define MROWS   (BATCH * LSEQ)          // 8192
#define SCALE   0.03125f                // 1/sqrt(1024)
#define NEGBIG  (-3.0e38f)

using bf16x8 = __attribute__((ext_vector_type(8))) short;
using f32x4  = __attribute__((ext_vector_type(4))) float;

// Truncation split: x ~= hi + lo with hi,lo bf16; residual <= 2^-16*|x|.
__device__ __forceinline__ void split8(float4 f0, float4 f1, uint4& H, uint4& L) {
    float f[8] = {f0.x, f0.y, f0.z, f0.w, f1.x, f1.y, f1.z, f1.w};
    unsigned h[8], l[8];
    #pragma unroll
    for (int i = 0; i < 8; ++i) {
        unsigned u = __float_as_uint(f[i]);
        h[i] = u >> 16;
        float hf = __uint_as_float(u & 0xffff0000u);
        l[i] = __float_as_uint(f[i] - hf) >> 16;
    }
    H = make_uint4(h[0] | (h[1] << 16), h[2] | (h[3] << 16),
                   h[4] | (h[5] << 16), h[6] | (h[7] << 16));
    L = make_uint4(l[0] | (l[1] << 16), l[2] | (l[3] << 16),
                   l[4] | (l[5] << 16), l[6] | (l[7] << 16));
}

// ---------------------------------------------------------------------------
// Kernel 1: per-head QKV projections (fp32 vector — unchanged, verified).
// ---------------------------------------------------------------------------
__global__ __launch_bounds__(256) void qkv_proj_kernel(
    const float* __restrict__ Xq, const float* __restrict__ Xk, const float* __restrict__ Xv,
    const float* __restrict__ Wq, const float* __restrict__ Wk, const float* __restrict__ Wv,
    float* __restrict__ Sq, float* __restrict__ Sk, float* __restrict__ Sv)
{
    const int which = blockIdx.z;
    const float* __restrict__ X = (which == 0) ? Xq : (which == 1) ? Xk : Xv;
    const float* __restrict__ W = (which == 0) ? Wq : (which == 1) ? Wk : Wv;
    float* __restrict__ S       = (which == 0) ? Sq : (which == 1) ? Sk : Sv;

    const int h  = blockIdx.x;
    const int m0 = blockIdx.y * 64;

    __shared__ float As[32][68];   // [k][m], padded
    __shared__ float Bs[32][68];   // [k][n], padded

    const int tid = threadIdx.x;
    const int tx  = tid & 15;
    const int ty  = tid >> 4;

    const int mA  = tid >> 2;
    const int kqA = (tid & 3) * 8;
    const int dB  = tid >> 4;
    const int nqB = (tid & 15) * 4;

    const float* Wh = W + (size_t)h * (D_MODEL * DK);

    float acc[4][4] = {{0.f, 0.f, 0.f, 0.f}, {0.f, 0.f, 0.f, 0.f},
                       {0.f, 0.f, 0.f, 0.f}, {0.f, 0.f, 0.f, 0.f}};

    for (int k0 = 0; k0 < D_MODEL; k0 += 32) {
        float4 a0 = *(const float4*)(X + (size_t)(m0 + mA) * D_MODEL + k0 + kqA);
        float4 a1 = *(const float4*)(X + (size_t)(m0 + mA) * D_MODEL + k0 + kqA + 4);
        float4 b0 = *(const float4*)(Wh + (size_t)(k0 + dB) * DK + nqB);
        float4 b1 = *(const float4*)(Wh + (size_t)(k0 + dB + 16) * DK + nqB);
        As[kqA + 0][mA] = a0.x; As[kqA + 1][mA] = a0.y;
        As[kqA + 2][mA] = a0.z; As[kqA + 3][mA] = a0.w;
        As[kqA + 4][mA] = a1.x; As[kqA + 5][mA] = a1.y;
        As[kqA + 6][mA] = a1.z; As[kqA + 7][mA] = a1.w;
        *(float4*)&Bs[dB][nqB]      = b0;
        *(float4*)&Bs[dB + 16][nqB] = b1;
        __syncthreads();
        #pragma unroll
        for (int kk = 0; kk < 32; ++kk) {
            float4 av = *(const float4*)&As[kk][ty * 4];
            float4 bv = *(const float4*)&Bs[kk][tx * 4];
            float a[4] = {av.x, av.y, av.z, av.w};
            float b[4] = {bv.x, bv.y, bv.z, bv.w};
            #pragma unroll
            for (int i = 0; i < 4; ++i)
                #pragma unroll
                for (int j = 0; j < 4; ++j)
                    acc[i][j] += a[i] * b[j];
        }
        __syncthreads();
    }

    const int b  = m0 >> 10;
    const int l0 = m0 & 1023;
    float* Sb = S + (size_t)(h * BATCH + b) * LSEQ * DK;
    #pragma unroll
    for (int i = 0; i < 4; ++i) {
        int l = l0 + ty * 4 + i;
        float4 o = {acc[i][0], acc[i][1], acc[i][2], acc[i][3]};
        *(float4*)(Sb + (size_t)l * DK + tx * 4) = o;
    }
}

// ---------------------------------------------------------------------------
// Kernel 2: attention via MFMA with split-bf16 (bf16x3) precision.
// Block = 64 q-rows x (h,b); 4 waves, each owning 16 q-rows.
// LDS fragment layout for all operands: [kgrp][row][8] (16B contiguous frags).
//   A-frag (lane l): row = l&15, k = 8*(l>>4)+i   -> Qh/Ql, Ph/Pl
//   B-frag (lane l): col = l&15, k = 8*(l>>4)+i   -> Kh/Kl, Vh/Vl
//   C/D: col = l&15, row = 4*(l>>4)+reg           (verified layout)
// ---------------------------------------------------------------------------
__global__ __launch_bounds__(256) void attn_mfma_kernel(
    const float* __restrict__ QS, const float* __restrict__ KS, const float* __restrict__ VS,
    const unsigned char* __restrict__ mask,
    float* __restrict__ attns, float* __restrict__ OH)
{
    const int qt = blockIdx.x;       // 0..15
    const int hb = blockIdx.y;       // h*8 + b
    const int h  = hb >> 3;
    const int b  = hb & 7;
    const int q0 = qt * 64;

    __shared__ __align__(16) unsigned short Qh[8][64][8], Ql[8][64][8];
    __shared__ __align__(16) unsigned short Kh[8][64][8], Kl[8][64][8];
    __shared__ __align__(16) unsigned short Vh[8][64][8], Vl[8][64][8];
    __shared__ __align__(16) unsigned short Ph[8][64][8], Pl[8][64][8];
    __shared__ unsigned char Msk[64][64];
    __shared__ int mflag[4];

    const int tid  = threadIdx.x;
    const int w    = tid >> 6;       // wave 0..3 -> q-rows 16w..16w+15
    const int lane = tid & 63;
    const int g    = lane >> 4;      // 0..3
    const int c    = lane & 15;

    const int srow = tid >> 2;       // staging row 0..63
    const int sj   = tid & 3;        // staging k-group quarter

    const float* Qg = QS + ((size_t)hb * LSEQ + q0) * DK;
    const float* Kg = KS + (size_t)hb * LSEQ * DK;
    const float* Vg = VS + (size_t)hb * LSEQ * DK;
    const unsigned char* Mg = mask + (size_t)b * LSEQ * LSEQ + (size_t)q0 * LSEQ;
    float* Ag = attns + ((size_t)hb * LSEQ + q0) * LSEQ;

    // ---- stage Q (resident for the whole kernel) ----
    #pragma unroll
    for (int jj = 0; jj < 2; ++jj) {
        const int dg = sj + jj * 4;
        float4 f0 = *(const float4*)(Qg + (size_t)srow * DK + dg * 8);
        float4 f1 = *(const float4*)(Qg + (size_t)srow * DK + dg * 8 + 4);
        uint4 H, L; split8(f0, f1, H, L);
        *(uint4*)&Qh[dg][srow][0] = H;
        *(uint4*)&Ql[dg][srow][0] = L;
    }

    float mrun[4], srun[4];
    #pragma unroll
    for (int r = 0; r < 4; ++r) { mrun[r] = NEGBIG; srun[r] = 0.f; }

    // =================== pass 1: row max + sum of exp ===================
    for (int kt = 0; kt < 16; ++kt) {
        #pragma unroll
        for (int jj = 0; jj < 2; ++jj) {
            const int dg = sj + jj * 4;
            const float* kp = Kg + (size_t)(kt * 64 + srow) * DK + dg * 8;
            float4 f0 = *(const float4*)kp;
            float4 f1 = *(const float4*)(kp + 4);
            uint4 H, L; split8(f0, f1, H, L);
            *(uint4*)&Kh[dg][srow][0] = H;
            *(uint4*)&Kl[dg][srow][0] = L;
        }
        uint4 mv = *(const uint4*)(Mg + (size_t)srow * LSEQ + kt * 64 + sj * 16);
        *(uint4*)&Msk[srow][sj * 16] = mv;
        unsigned long long bal = __ballot((mv.x | mv.y | mv.z | mv.w) != 0u);
        if (lane == 0) mflag[w] = (bal != 0ull);
        __syncthreads();
        const int anym = mflag[0] | mflag[1] | mflag[2] | mflag[3];

        f32x4 sc[4];
        #pragma unroll
        for (int t = 0; t < 4; ++t) sc[t] = (f32x4){0.f, 0.f, 0.f, 0.f};
        #pragma unroll
        for (int s = 0; s < 2; ++s) {
            const int dg = 4 * s + g;
            bf16x8 ah = *(const bf16x8*)&Qh[dg][16 * w + c][0];
            bf16x8 al = *(const bf16x8*)&Ql[dg][16 * w + c][0];
            #pragma unroll
            for (int t = 0; t < 4; ++t) {
                bf16x8 bh = *(const bf16x8*)&Kh[dg][16 * t + c][0];
                bf16x8 bl = *(const bf16x8*)&Kl[dg][16 * t + c][0];
                sc[t] = __builtin_amdgcn_mfma_f32_16x16x32_bf16(ah, bh, sc[t], 0, 0, 0);
                sc[t] = __builtin_amdgcn_mfma_f32_16x16x32_bf16(ah, bl, sc[t], 0, 0, 0);
                sc[t] = __builtin_amdgcn_mfma_f32_16x16x32_bf16(al, bh, sc[t], 0, 0, 0);
            }
        }
        #pragma unroll
        for (int r = 0; r < 4; ++r) {
            float s0 = sc[0][r] * SCALE, s1 = sc[1][r] * SCALE;
            float s2 = sc[2][r] * SCALE, s3 = sc[3][r] * SCALE;
            if (anym) {
                const unsigned char* mb = &Msk[16 * w + 4 * g + r][0];
                if (mb[c])      s0 = NEGBIG;
                if (mb[16 + c]) s1 = NEGBIG;
                if (mb[32 + c]) s2 = NEGBIG;
                if (mb[48 + c]) s3 = NEGBIG;
            }
            float tm = fmaxf(fmaxf(s0, s1), fmaxf(s2, s3));
            float nm = fmaxf(mrun[r], tm);
            srun[r] = srun[r] * __expf(mrun[r] - nm) +
                      __expf(s0 - nm) + __expf(s1 - nm) + __expf(s2 - nm) + __expf(s3 - nm);
            mrun[r] = nm;
        }
        __syncthreads();
    }

    // ---- combine (m,s) across the 16 lanes sharing each row group ----
    float mfin[4], sinv[4];
    #pragma unroll
    for (int r = 0; r < 4; ++r) {
        float m = mrun[r], s = srun[r];
        #pragma unroll
        for (int off = 1; off < 16; off <<= 1) {
            float m2 = __shfl_xor(m, off);
            float s2 = __shfl_xor(s, off);
            float nm = fmaxf(m, m2);
            s = s * __expf(m - nm) + s2 * __expf(m2 - nm);
            m = nm;
        }
        mfin[r] = m;
        sinv[r] = 1.f / s;
    }

    // =================== pass 2: P, attns write, PV ===================
    f32x4 acc[4];
    #pragma unroll
    for (int t = 0; t < 4; ++t) acc[t] = (f32x4){0.f, 0.f, 0.f, 0.f};

    for (int kt = 0; kt < 16; ++kt) {
        #pragma unroll
        for (int jj = 0; jj < 2; ++jj) {
            const int dg = sj + jj * 4;
            const float* kp = Kg + (size_t)(kt * 64 + srow) * DK + dg * 8;
            float4 f0 = *(const float4*)kp;
            float4 f1 = *(const float4*)(kp + 4);
            uint4 H, L; split8(f0, f1, H, L);
            *(uint4*)&Kh[dg][srow][0] = H;
            *(uint4*)&Kl[dg][srow][0] = L;
        }
        {   // V staging with transpose: pairs of rows packed as b32 writes
            const int lp = tid >> 3;          // row pair 0..31 -> l = 2*lp
            const int vc = (tid & 7) * 8;     // v chunk
            const float* vp = Vg + (size_t)(kt * 64 + 2 * lp) * DK + vc;
            float4 a0 = *(const float4*)vp;
            float4 a1 = *(const float4*)(vp + 4);
            float4 b0 = *(const float4*)(vp + DK);
            float4 b1 = *(const float4*)(vp + DK + 4);
            uint4 H0, L0, H1, L1;
            split8(a0, a1, H0, L0);
            split8(b0, b1, H1, L1);
            const unsigned* ph0 = (const unsigned*)&H0;
            const unsigned* pl0 = (const unsigned*)&L0;
            const unsigned* ph1 = (const unsigned*)&H1;
            const unsigned* pl1 = (const unsigned*)&L1;
            const int kg = lp >> 2, k7 = (2 * lp) & 7;
            #pragma unroll
            for (int v = 0; v < 8; ++v) {
                unsigned h0v = (ph0[v >> 1] >> ((v & 1) * 16)) & 0xffffu;
                unsigned h1v = (ph1[v >> 1] >> ((v & 1) * 16)) & 0xffffu;
                unsigned l0v = (pl0[v >> 1] >> ((v & 1) * 16)) & 0xffffu;
                unsigned l1v = (pl1[v >> 1] >> ((v & 1) * 16)) & 0xffffu;
                *(unsigned*)&Vh[kg][vc + v][k7] = h0v | (h1v << 16);
                *(unsigned*)&Vl[kg][vc + v][k7] = l0v | (l1v << 16);
            }
        }
        uint4 mv = *(const uint4*)(Mg + (size_t)srow * LSEQ + kt * 64 + sj * 16);
        *(uint4*)&Msk[srow][sj * 16] = mv;
        unsigned long long bal = __ballot((mv.x | mv.y | mv.z | mv.w) != 0u);
        if (lane == 0) mflag[w] = (bal != 0ull);
        __syncthreads();
        const int anym = mflag[0] | mflag[1] | mflag[2] | mflag[3];

        f32x4 sc[4];
        #pragma unroll
        for (int t = 0; t < 4; ++t) sc[t] = (f32x4){0.f, 0.f, 0.f, 0.f};
        #pragma unroll
        for (int s = 0; s < 2; ++s) {
            const int dg = 4 * s + g;
            bf16x8 ah = *(const bf16x8*)&Qh[dg][16 * w + c][0];
            bf16x8 al = *(const bf16x8*)&Ql[dg][16 * w + c][0];
            #pragma unroll
            for (int t = 0; t < 4; ++t) {
                bf16x8 bh = *(const bf16x8*)&Kh[dg][16 * t + c][0];
                bf16x8 bl = *(const bf16x8*)&Kl[dg][16 * t + c][0];
                sc[t] = __builtin_amdgcn_mfma_f32_16x16x32_bf16(ah, bh, sc[t], 0, 0, 0);
                sc[t] = __builtin_amdgcn_mfma_f32_16x16x32_bf16(ah, bl, sc[t], 0, 0, 0);
                sc[t] = __builtin_amdgcn_mfma_f32_16x16x32_bf16(al, bh, sc[t], 0, 0, 0);
            }
        }
        #pragma unroll
        for (int r = 0; r < 4; ++r) {
            const int qrow = 16 * w + 4 * g + r;
            #pragma unroll
            for (int t = 0; t < 4; ++t) {
                float sv = sc[t][r] * SCALE;
                float p  = __expf(sv - mfin[r]) * sinv[r];
                if (anym && Msk[qrow][16 * t + c]) p = 0.f;
                unsigned u = __float_as_uint(p);
                unsigned short phv = (unsigned short)(u >> 16);
                float hf = __uint_as_float(u & 0xffff0000u);
                unsigned short plv = (unsigned short)(__float_as_uint(p - hf) >> 16);
                Ph[2 * t + (c >> 3)][qrow][c & 7] = phv;
                Pl[2 * t + (c >> 3)][qrow][c & 7] = plv;
            }
        }
        __syncthreads();

        // coalesced attns write (reconstruct fp32 = hi + lo)
        #pragma unroll
        for (int jj = 0; jj < 2; ++jj) {
            const int dg = sj + jj * 4;
            uint4 H = *(const uint4*)&Ph[dg][srow][0];
            uint4 L = *(const uint4*)&Pl[dg][srow][0];
            const unsigned* hp = (const unsigned*)&H;
            const unsigned* lq = (const unsigned*)&L;
            float o[8];
            #pragma unroll
            for (int v = 0; v < 8; ++v) {
                unsigned hv = (hp[v >> 1] >> ((v & 1) * 16)) << 16;
                unsigned lv = (lq[v >> 1] >> ((v & 1) * 16)) << 16;
                o[v] = __uint_as_float(hv) + __uint_as_float(lv);
            }
            *(float4*)(Ag + (size_t)srow * LSEQ + kt * 64 + dg * 8)     = make_float4(o[0], o[1], o[2], o[3]);
            *(float4*)(Ag + (size_t)srow * LSEQ + kt * 64 + dg * 8 + 4) = make_float4(o[4], o[5], o[6], o[7]);
        }

        // PV MFMA
        #pragma unroll
        for (int s = 0; s < 2; ++s) {
            const int kg = 4 * s + g;
            bf16x8 pah = *(const bf16x8*)&Ph[kg][16 * w + c][0];
            bf16x8 pal = *(const bf16x8*)&Pl[kg][16 * w + c][0];
            #pragma unroll
            for (int t = 0; t < 4; ++t) {
                bf16x8 vbh = *(const bf16x8*)&Vh[kg][16 * t + c][0];
                bf16x8 vbl = *(const bf16x8*)&Vl[kg][16 * t + c][0];
                acc[t] = __builtin_amdgcn_mfma_f32_16x16x32_bf16(pah, vbh, acc[t], 0, 0, 0);
                acc[t] = __builtin_amdgcn_mfma_f32_16x16x32_bf16(pah, vbl, acc[t], 0, 0, 0);
                acc[t] = __builtin_amdgcn_mfma_f32_16x16x32_bf16(pal, vbh, acc[t], 0, 0, 0);
            }
        }
        __syncthreads();
    }

    // ---- write OH[b][l][h*64+v] from C-layout ----
    float* Og = OH + ((size_t)b * LSEQ + q0) * D_MODEL + h * DK;
    #pragma unroll
    for (int t = 0; t < 4; ++t)
        #pragma unroll
        for (int r = 0; r < 4; ++r)
            Og[(size_t)(16 * w + 4 * g + r) * D_MODEL + 16 * t + c] = acc[t][r];
}

// ---------------------------------------------------------------------------
// Kernel 3: output projection + bias + residual (fp32 vector — unchanged).
// ---------------------------------------------------------------------------
__global__ __launch_bounds__(256) void out_proj_kernel(
    const float* __restrict__ O, const float* __restrict__ Pw, const float* __restrict__ pb,
    const float* __restrict__ R, float* __restrict__ Xo)
{
    const int n0 = blockIdx.x * 64;
    const int m0 = blockIdx.y * 64;

    __shared__ float As[32][68];
    __shared__ float Bs[32][68];

    const int tid = threadIdx.x;
    const int tx  = tid & 15;
    const int ty  = tid >> 4;

    const int rA = tid >> 2;
    const int kq = (tid & 3) * 8;

    float acc[4][4] = {{0.f, 0.f, 0.f, 0.f}, {0.f, 0.f, 0.f, 0.f},
                       {0.f, 0.f, 0.f, 0.f}, {0.f, 0.f, 0.f, 0.f}};

    for (int k0 = 0; k0 < D_MODEL; k0 += 32) {
        float4 a0 = *(const float4*)(O  + (size_t)(m0 + rA) * D_MODEL + k0 + kq);
        float4 a1 = *(const float4*)(O  + (size_t)(m0 + rA) * D_MODEL + k0 + kq + 4);
        float4 b0 = *(const float4*)(Pw + (size_t)(n0 + rA) * D_MODEL + k0 + kq);
        float4 b1 = *(const float4*)(Pw + (size_t)(n0 + rA) * D_MODEL + k0 + kq + 4);
        As[kq + 0][rA] = a0.x; As[kq + 1][rA] = a0.y;
        As[kq + 2][rA] = a0.z; As[kq + 3][rA] = a0.w;
        As[kq + 4][rA] = a1.x; As[kq + 5][rA] = a1.y;
        As[kq + 6][rA] = a1.z; As[kq + 7][rA] = a1.w;
        Bs[kq + 0][rA] = b0.x; Bs[kq + 1][rA] = b0.y;
        Bs[kq + 2][rA] = b0.z; Bs[kq + 3][rA] = b0.w;
        Bs[kq + 4][rA] = b1.x; Bs[kq + 5][rA] = b1.y;
        Bs[kq + 6][rA] = b1.z; Bs[kq + 7][rA] = b1.w;
        __syncthreads();
        #pragma unroll
        for (int kk = 0; kk < 32; ++kk) {
            float4 av = *(const float4*)&As[kk][ty * 4];
            float4 bv = *(const float4*)&Bs[kk][tx * 4];
            float a[4] = {av.x, av.y, av.z, av.w};
            float b[4] = {bv.x, bv.y, bv.z, bv.w};
            #pragma unroll
            for (int i = 0; i < 4; ++i)
                #pragma unroll
                for (int j = 0; j < 4; ++j)
                    acc[i][j] += a[i] * b[j];
        }
        __syncthreads();
    }

    #pragma unroll
    for (int i = 0; i < 4; ++i) {
        int m = m0 + ty * 4 + i;
        int n = n0 + tx * 4;
        float4 pbv = *(const float4*)(pb + n);
        float4 rv  = *(const float4*)(R + (size_t)m * D_MODEL + n);
        float4 o;
        o.x = acc[i][0] + pbv.x + rv.x;
        o.y = acc[i][1] + pbv.y + rv.y;
        o.z = acc[i][2] + pbv.z + rv.z;
        o.w = acc[i][3] + pbv.w + rv.w;
        *(float4*)(Xo + (size_t)m * D_MODEL + n) = o;
    }
}

// ---------------------------------------------------------------------------
// Kernel 4: LayerNorm (unchanged).
// ---------------------------------------------------------------------------
__global__ __launch_bounds__(256) void ln_kernel(
    float* __restrict__ x, const float* __restrict__ g, const float* __restrict__ bt)
{
    const int row = blockIdx.x;
    float* xr = x + (size_t)row * D_MODEL;
    const int tid = threadIdx.x;

    __shared__ float red[4];

    float4 v = ((const float4*)xr)[tid];
    float s = v.x + v.y + v.z + v.w;
    #pragma unroll
    for (int o = 1; o < 64; o <<= 1) s += __shfl_xor(s, o);
    if ((tid & 63) == 0) red[tid >> 6] = s;
    __syncthreads();
    s = red[0] + red[1] + red[2] + red[3];
    const float mean = s * (1.f / 1024.f);

    float dx = v.x - mean, dy = v.y - mean, dz = v.z - mean, dw = v.w - mean;
    float sq = dx * dx + dy * dy + dz * dz + dw * dw;
    #pragma unroll
    for (int o = 1; o < 64; o <<= 1) sq += __shfl_xor(sq, o);
    __syncthreads();
    if ((tid & 63) == 0) red[tid >> 6] = sq;
    __syncthreads();
    sq = red[0] + red[1] + red[2] + red[3];
    const float rstd = rsqrtf(sq * (1.f / 1024.f) + 1e-5f);

    float4 gv = ((const float4*)g)[tid];
    float4 bv = ((const float4*)bt)[tid];
    float4 o4;
    o4.x = dx * rstd * gv.x + bv.x;
    o4.y = dy * rstd * gv.y + bv.y;
    o4.z = dz * rstd * gv.z + bv.z;
    o4.w = dw * rstd * gv.w + bv.w;
    ((float4*)xr)[tid] = o4;
}

// ---------------------------------------------------------------------------
extern "C" void kernel_launch(void* const* d_in, const int* in_sizes, int n_in,
                              void* d_out, int out_size, void* d_ws, size_t ws_size,
                              hipStream_t stream)
{
    const float* q      = (const float*)d_in[0];
    const float* k      = (const float*)d_in[1];
    const float* v      = (const float*)d_in[2];
    const unsigned char* mask = (const unsigned char*)d_in[3];
    const float* w_qs   = (const float*)d_in[4];
    const float* w_ks   = (const float*)d_in[5];
    const float* w_vs   = (const float*)d_in[6];
    const float* proj_w = (const float*)d_in[7];
    const float* proj_b = (const float*)d_in[8];
    const float* ln_g   = (const float*)d_in[9];
    const float* ln_b   = (const float*)d_in[10];

    float* outputs = (float*)d_out;
    float* attns   = (float*)d_out + (size_t)BATCH * LSEQ * D_MODEL;

    float* qs = (float*)d_ws;
    float* ks = qs + (size_t)N_HEAD * BATCH * LSEQ * DK;
    float* vs = ks + (size_t)N_HEAD * BATCH * LSEQ * DK;
    float* oh = vs + (size_t)N_HEAD * BATCH * LSEQ * DK;

    dim3 blk(256);
    qkv_proj_kernel<<<dim3(N_HEAD, MROWS / 64, 3), blk, 0, stream>>>(
        q, k, v, w_qs, w_ks, w_vs, qs, ks, vs);
    attn_mfma_kernel<<<dim3(LSEQ / 64, N_HEAD * BATCH), blk, 0, stream>>>(
        qs, ks, vs, mask, attns, oh);
    out_proj_kernel<<<dim3(D_MODEL / 64, MROWS / 64), blk, 0, stream>>>(
        oh, proj_w, proj_b, q, outputs);
    ln_kernel<<<dim3(MROWS), blk, 0, stream>>>(outputs, ln_g, ln_b);
}